// Round 6
// baseline (976.425 us; speedup 1.0000x reference)
//
#include <hip/hip_runtime.h>
#include <math.h>

#define NS 4096
#define NF 512
#define NB 16
#define NC 10
#define HEMPTY 0xFFFFFFFFu

// Path A ws layout: Xt[16][512][4096] f32, then stats[8192][16] f32, then counts[16][10] i32
#define XT_BYTES ((size_t)NB * NF * NS * 4)     // 128 MiB
#define STATS_BYTES (NB * NF * 16 * 4)          // 512 KiB
#define CNT_BYTES (NB * NC * 4)
#define WS_A (XT_BYTES + STATS_BYTES + CNT_BYTES)
#define HS_A 6144
#define HS_B 8192

// ---------------- K0: per-(b,c) class counts (one block per b) ----------------
__global__ void count_classes_kernel(const int* __restrict__ y, int* __restrict__ counts) {
    __shared__ int hist[NC];
    const int b = blockIdx.x;
    if (threadIdx.x < NC) hist[threadIdx.x] = 0;
    __syncthreads();
    for (int s = threadIdx.x; s < NS; s += 256) atomicAdd(&hist[y[b * NS + s]], 1);
    __syncthreads();
    if (threadIdx.x < NC) counts[b * NC + threadIdx.x] = hist[threadIdx.x];
}

__device__ __forceinline__ int wred_add_i(int v) {
    #pragma unroll
    for (int off = 32; off > 0; off >>= 1) v += __shfl_down(v, off, 64);
    return v;
}

// ================= PATH A =================
// K1: 64x64 tile transpose + fused stats. grid = NB*64*8, 256 threads, ~16.6 KB LDS.
__launch_bounds__(256)
__global__ void transpose_stats_kernel(const float* __restrict__ X,
                                       const int* __restrict__ y,
                                       float* __restrict__ Xt,
                                       float* __restrict__ statsb) {
    __shared__ float buf[64][65];                 // tile, then reused for cross-wave reduce
    float* flat = &buf[0][0];

    const int w  = blockIdx.x;                    // b-major
    const int b  = w >> 9;
    const int rc = (w >> 3) & 63;
    const int fc = w & 7;
    const int r0 = rc << 6, f0 = fc << 6;
    const int tid = threadIdx.x, wv = tid >> 6, lane = tid & 63;

    const float* Xp = X + ((size_t)b * NS + r0) * NF + f0 + lane;
    const int*   yp = y + b * NS + r0;

    float sum = 0.f, sq = 0.f, ab = 0.f, nn = 0.f, mx = 0.f;
    float cs[NC];
    #pragma unroll
    for (int c = 0; c < NC; c++) cs[c] = 0.f;

    // wave wv owns rows {wv + 4*i}; lanes span 64 features -> coalesced, y wave-uniform
    #pragma unroll
    for (int h = 0; h < 2; h++) {
        float xv[8]; int yv[8];
        #pragma unroll
        for (int k = 0; k < 8; k++) {             // 8 loads in flight
            const int rl = wv + 4 * (h * 8 + k);
            xv[k] = Xp[(size_t)rl * NF];
            yv[k] = yp[rl];
        }
        #pragma unroll
        for (int k = 0; k < 8; k++) {
            const int rl = wv + 4 * (h * 8 + k);
            float x = xv[k];
            if (x != x) { nn += 1.f; x = 0.f; }                    // nan_to_num
            if (__float_as_uint(x) == 0x80000000u) x = 0.f;        // canonicalize -0
            buf[rl][lane] = x;
            sum += x; sq = fmaf(x, x, sq);
            const float a = fabsf(x); ab += a; mx = fmaxf(mx, a);
            const int yu = __builtin_amdgcn_readfirstlane(yv[k]);  // wave-uniform class
            #pragma unroll
            for (int c = 0; c < NC; c++)
                if (yu == c) cs[c] += x;                           // scalar-branch guarded
        }
    }
    __syncthreads();

    // transposed write: wave wv writes cols {wv+4j}; lanes span rows -> coalesced 256B
    #pragma unroll
    for (int j = 0; j < 16; j++) {
        const int cl = wv + 4 * j;
        Xt[((size_t)(b * NF + f0 + cl)) * NS + r0 + lane] = buf[lane][cl];
    }
    __syncthreads();

    // cross-wave stat reduce through reused LDS: idx = s*272 + wv*68 + lane (max 4075 < 4160)
    {
        float a[15];
        a[0] = sum; a[1] = sq; a[2] = ab; a[3] = nn; a[4] = mx;
        #pragma unroll
        for (int c = 0; c < NC; c++) a[5 + c] = cs[c];
        #pragma unroll
        for (int s = 0; s < 15; s++) flat[s * 272 + wv * 68 + lane] = a[s];
    }
    __syncthreads();

    if (tid < 64) {
        float* sp = statsb + ((size_t)(b * NF + f0 + tid)) * 16;
        #pragma unroll
        for (int s = 0; s < 15; s++) {
            const float v0 = flat[s * 272 + 0 * 68 + tid];
            const float v1 = flat[s * 272 + 1 * 68 + tid];
            const float v2 = flat[s * 272 + 2 * 68 + tid];
            const float v3 = flat[s * 272 + 3 * 68 + tid];
            if (s == 4) atomicMax((int*)(sp + 4), __float_as_int(fmaxf(fmaxf(v0, v1), fmaxf(v2, v3))));
            else        atomicAdd(sp + s, (v0 + v1) + (v2 + v3));
        }
    }
}

// K2: coalesced hash-unique over Xt + finalize + MLP. one block per column, 24.6 KB LDS.
__device__ __forceinline__ void hins_a(unsigned int* h, float x, int& u) {
    const unsigned int pat = __float_as_uint(x);         // already canonical (no NaN, no -0)
    unsigned int slot = __umulhi(pat * 2654435761u, HS_A);
    for (;;) {
        const unsigned int old = atomicCAS(h + slot, HEMPTY, pat);
        if (old == HEMPTY) { u++; break; }
        if (old == pat) break;
        if (++slot == HS_A) slot = 0;
    }
}

__launch_bounds__(256)
__global__ void unique_mlp_t_kernel(const float* __restrict__ Xt,
                                    const float* __restrict__ statsb,
                                    const int* __restrict__ counts,
                                    const float* __restrict__ w1,
                                    const float* __restrict__ b1,
                                    const float* __restrict__ w2,
                                    const float* __restrict__ b2,
                                    float* __restrict__ out) {
    __shared__ unsigned int hash[HS_A];
    __shared__ float redu[4];
    __shared__ float stats_s[6];
    __shared__ float h_s[64];

    const int g = blockIdx.x;                    // g = b*NF + f
    const int b = g >> 9;
    const int tid = threadIdx.x, wv = tid >> 6, lane = tid & 63;

    {
        uint4* hp = (uint4*)hash;
        #pragma unroll
        for (int i = 0; i < 6; i++) hp[tid + i * 256] = make_uint4(HEMPTY, HEMPTY, HEMPTY, HEMPTY);
    }
    __syncthreads();

    const float4* Xp = (const float4*)(Xt + (size_t)g * NS);
    float4 v[4];
    #pragma unroll
    for (int k = 0; k < 4; k++) v[k] = Xp[tid + k * 256];   // fully coalesced, 16B/lane

    int uniq = 0;
    #pragma unroll
    for (int k = 0; k < 4; k++) {
        hins_a(hash, v[k].x, uniq);
        hins_a(hash, v[k].y, uniq);
        hins_a(hash, v[k].z, uniq);
        hins_a(hash, v[k].w, uniq);
    }
    const int u = wred_add_i(uniq);
    if (lane == 0) redu[wv] = (float)u;
    __syncthreads();

    if (tid == 0) {
        const float n_unique = redu[0] + redu[1] + redu[2] + redu[3];
        const float* sp = statsb + (size_t)g * 16;
        const float invS = 1.f / (float)NS;
        const float gmean    = sp[0] * invS;
        const float variance = fmaxf(sp[1] * invS - gmean * gmean, 0.f);
        const float mean_abs = sp[2] * invS;
        const float missing  = sp[3] * invS;
        const float max_abs  = sp[4];
        float between = 0.f;
        #pragma unroll
        for (int c = 0; c < NC; c++) {
            const float cnt = (float)counts[b * NC + c];
            const float cm  = sp[5 + c] / fmaxf(cnt, 1.f);
            const float d   = cm - gmean;
            between += cnt * d * d;
        }
        between *= invS;
        const float target = between / fmaxf(variance, 1e-6f);
        float st[6] = { target, missing, n_unique * invS, variance, mean_abs, max_abs };
        #pragma unroll
        for (int i = 0; i < 6; i++) {
            float vv = st[i];
            if (!(fabsf(vv) < INFINITY)) vv = 0.f;     // nan_to_num
            stats_s[i] = vv;
        }
    }
    __syncthreads();

    if (tid < 64) {
        float z = b1[tid];
        #pragma unroll
        for (int i = 0; i < 6; i++) z = fmaf(stats_s[i], w1[i * 64 + tid], z);
        h_s[tid] = 0.5f * z * (1.f + erff(z * 0.70710678118654752440f));
    }
    __syncthreads();
    if (tid < 128) {
        float o = b2[tid];
        #pragma unroll
        for (int j = 0; j < 64; j++) o = fmaf(h_s[j], w2[j * 128 + tid], o);
        out[(size_t)g * 128 + tid] = o;
    }
}

// ================= PATH B (fallback, R4-proven) =================
__launch_bounds__(256)
__global__ void stats_pass_kernel(const float* __restrict__ X,
                                  const int* __restrict__ y,
                                  float* __restrict__ statsb) {
    const int w  = blockIdx.x;
    const int b  = w >> 5;
    const int sc = (w >> 1) & 15;
    const int fh = w & 1;
    const int tid = threadIdx.x;
    const int f  = fh * 256 + tid;

    const float* Xp = X + ((size_t)b * NS + (size_t)sc * 256) * NF + f;
    const int*   yp = y + b * NS + sc * 256;

    float sum = 0.f, sumsq = 0.f, sumabs = 0.f, nancnt = 0.f, maxab = 0.f;
    float cs[NC];
    #pragma unroll
    for (int c = 0; c < NC; c++) cs[c] = 0.f;

    for (int r0 = 0; r0 < 256; r0 += 8) {
        float xv[8];
        #pragma unroll
        for (int k = 0; k < 8; k++) xv[k] = Xp[(size_t)(r0 + k) * NF];
        #pragma unroll
        for (int k = 0; k < 8; k++) {
            float x = xv[k];
            const int yv = __builtin_amdgcn_readfirstlane(yp[r0 + k]);
            if (x != x) { nancnt += 1.f; x = 0.f; }
            sum += x;
            sumsq = fmaf(x, x, sumsq);
            const float a = fabsf(x);
            sumabs += a;
            maxab = fmaxf(maxab, a);
            #pragma unroll
            for (int c = 0; c < NC; c++)
                if (yv == c) cs[c] += x;
        }
    }
    float* sp = statsb + ((size_t)(b * NF + f)) * 16;
    atomicAdd(sp + 0, sum);
    atomicAdd(sp + 1, sumsq);
    atomicAdd(sp + 2, sumabs);
    atomicAdd(sp + 3, nancnt);
    atomicMax((int*)(sp + 4), __float_as_int(maxab));
    #pragma unroll
    for (int c = 0; c < NC; c++) atomicAdd(sp + 5 + c, cs[c]);
}

__launch_bounds__(512, 8)
__global__ void unique_mlp_s_kernel(const float* __restrict__ X,
                                    const float* __restrict__ statsb,
                                    const int* __restrict__ counts,
                                    const float* __restrict__ w1,
                                    const float* __restrict__ b1,
                                    const float* __restrict__ w2,
                                    const float* __restrict__ b2,
                                    float* __restrict__ out) {
    __shared__ unsigned int hash[HS_B];
    __shared__ float redu[8];
    __shared__ float stats_s[6];
    __shared__ float h_s[64];

    const int w = blockIdx.x;
    const int g = (w & 7) * 1024 + (w >> 3);
    const int b = g >> 9;
    const int f = g & (NF - 1);
    const int tid = threadIdx.x;

    {
        uint4* hp = (uint4*)hash;
        #pragma unroll
        for (int i = 0; i < (HS_B / 4) / 512; i++)
            hp[tid + i * 512] = make_uint4(HEMPTY, HEMPTY, HEMPTY, HEMPTY);
    }
    __syncthreads();

    const float* Xp = X + (size_t)b * NS * NF + f;
    float xv[8];
    #pragma unroll
    for (int k = 0; k < 8; k++) xv[k] = Xp[(size_t)(k * 512 + tid) * NF];

    int uniq = 0;
    #pragma unroll
    for (int k = 0; k < 8; k++) {
        float x = xv[k];
        if (x != x) x = 0.f;
        unsigned int pat = __float_as_uint(x);
        if (pat == 0x80000000u) pat = 0u;
        unsigned int slot = (pat * 2654435761u) >> 19;
        for (;;) {
            const unsigned int old = atomicCAS(&hash[slot], HEMPTY, pat);
            if (old == HEMPTY) { uniq++; break; }
            if (old == pat) break;
            slot = (slot + 1) & (HS_B - 1);
        }
    }
    const int wave = tid >> 6, lane = tid & 63;
    const int u = wred_add_i(uniq);
    if (lane == 0) redu[wave] = (float)u;
    __syncthreads();

    if (tid == 0) {
        float n_unique = 0.f;
        #pragma unroll
        for (int i = 0; i < 8; i++) n_unique += redu[i];
        const float* sp = statsb + (size_t)g * 16;
        const float invS = 1.f / (float)NS;
        const float gmean    = sp[0] * invS;
        const float variance = fmaxf(sp[1] * invS - gmean * gmean, 0.f);
        const float mean_abs = sp[2] * invS;
        const float missing  = sp[3] * invS;
        const float max_abs  = sp[4];
        float between = 0.f;
        #pragma unroll
        for (int c = 0; c < NC; c++) {
            const float cnt = (float)counts[b * NC + c];
            const float cm  = sp[5 + c] / fmaxf(cnt, 1.f);
            const float d   = cm - gmean;
            between += cnt * d * d;
        }
        between *= invS;
        const float target = between / fmaxf(variance, 1e-6f);
        float st[6] = { target, missing, n_unique * invS, variance, mean_abs, max_abs };
        #pragma unroll
        for (int i = 0; i < 6; i++) {
            float v = st[i];
            if (!(fabsf(v) < INFINITY)) v = 0.f;
            stats_s[i] = v;
        }
    }
    __syncthreads();

    if (tid < 64) {
        float z = b1[tid];
        #pragma unroll
        for (int i = 0; i < 6; i++) z = fmaf(stats_s[i], w1[i * 64 + tid], z);
        h_s[tid] = 0.5f * z * (1.f + erff(z * 0.70710678118654752440f));
    }
    __syncthreads();
    if (tid < 128) {
        float o = b2[tid];
        #pragma unroll
        for (int j = 0; j < 64; j++) o = fmaf(h_s[j], w2[j * 128 + tid], o);
        out[(size_t)g * 128 + tid] = o;
    }
}

extern "C" void kernel_launch(void* const* d_in, const int* in_sizes, int n_in,
                              void* d_out, int out_size, void* d_ws, size_t ws_size,
                              hipStream_t stream) {
    const float* X  = (const float*)d_in[0];
    const int*   y  = (const int*)d_in[1];
    const float* w1 = (const float*)d_in[2];
    const float* b1 = (const float*)d_in[3];
    const float* w2 = (const float*)d_in[4];
    const float* b2 = (const float*)d_in[5];
    float* out = (float*)d_out;

    if (ws_size >= WS_A) {
        float* Xt     = (float*)d_ws;
        float* statsb = (float*)((char*)d_ws + XT_BYTES);
        int*   counts = (int*)((char*)d_ws + XT_BYTES + STATS_BYTES);
        hipMemsetAsync(statsb, 0, STATS_BYTES, stream);
        count_classes_kernel<<<NB, 256, 0, stream>>>(y, counts);
        transpose_stats_kernel<<<NB * 64 * 8, 256, 0, stream>>>(X, y, Xt, statsb);
        unique_mlp_t_kernel<<<NB * NF, 256, 0, stream>>>(Xt, statsb, counts, w1, b1, w2, b2, out);
    } else {
        float* statsb = (float*)d_ws;
        int*   counts = (int*)((char*)d_ws + STATS_BYTES);
        hipMemsetAsync(d_ws, 0, STATS_BYTES, stream);
        count_classes_kernel<<<NB, 256, 0, stream>>>(y, counts);
        stats_pass_kernel<<<NB * 16 * 2, 256, 0, stream>>>(X, y, statsb);
        unique_mlp_s_kernel<<<NB * NF, 512, 0, stream>>>(X, statsb, counts, w1, b1, w2, b2, out);
    }
}